// Round 10
// baseline (187.280 us; speedup 1.0000x reference)
//
#include <hip/hip_runtime.h>
#include <hip/hip_cooperative_groups.h>

namespace cg = cooperative_groups;

// Problem constants (fixed by the reference's setup_inputs):
//   B=128 batches, S=32768 sequence, P=65536 path steps.
#define NB 128
#define NS 32768
#define NP 65536
#define POS_W 5.0f

constexpr int MASK_WORDS = (NB * NS) / 32;   // 131072 words = 512 KB per mask plane
constexpr int WPB        = NS / 32;          // 1024 mask words per batch (4 KB)
constexpr int QPB        = 4;                // planes per batch
constexpr int BLOCKS     = NB * QPB;         // 512 blocks (2/CU -> coop-safe)
constexpr int THREADS    = 512;

// ws layout:
//   [0, MASK_WORDS*4)                  : global targets bitmap (tbits)
//   [MASK_WORDS*4, +QPB*MASK_WORDS*4)  : QPB partial gt-mask planes
//   [after planes, BLOCKS*4)           : per-block loss partials
//
// Journal: no hipMemsetAsync for small regions (R7); no mid-stream
// device-scope fences (R8, -25us). Cooperative single-dispatch replaces 4
// dependent graph nodes (R10).

__global__ __launch_bounds__(THREADS, 4)
void fused_kernel(const float* __restrict__ preds, const int* __restrict__ targets,
                  const int* __restrict__ pw, unsigned int* __restrict__ tbits_g,
                  unsigned int* __restrict__ pmask, float* __restrict__ partials,
                  float* __restrict__ out) {
    cg::grid_group grid = cg::this_grid();

    __shared__ unsigned int tbits[WPB];   // 4 KB (phase 2)
    __shared__ unsigned int gbits[WPB];   // 4 KB (phase 2)
    __shared__ float sacc[8];             // phase 3/4 block reduce

    const int tid   = threadIdx.x;        // 0..511
    const int bid   = blockIdx.x;         // 0..511
    const int lane  = tid & 63;
    const int wbase = tid & ~63;

    // ---- Phase 1: targets (16 MB) -> 512 KB bitmap via per-wave ballot ----
    {
        constexpr int NSEG = NB * NS / 64;              // 65536 segments
        const int gwid = (bid * THREADS + tid) >> 6;    // 4096 waves
        constexpr int NW = (BLOCKS * THREADS) >> 6;
        for (int s = gwid; s < NSEG; s += NW) {
            const unsigned long long m = __ballot(targets[(size_t)s * 64 + lane] != 0);
            if (lane == 0)       tbits_g[s * 2]     = (unsigned int)m;
            else if (lane == 32) tbits_g[s * 2 + 1] = (unsigned int)(m >> 32);
        }
    }
    grid.sync();

    // ---- Phase 2: gt planes. block = (batch b, plane q) ----
    {
        const int is64 = (pw[2 * (size_t)NP - 1] == 0);  // layout detect (uniform)
        const int q = bid & (QPB - 1);
        const int b = bid / QPB;

        tbits[tid]       = tbits_g[(size_t)b * WPB + tid];
        tbits[tid + 512] = tbits_g[(size_t)b * WPB + tid + 512];
        gbits[tid]       = 0u;
        gbits[tid + 512] = 0u;
        __syncthreads();

        constexpr int STEPS = NP / QPB;              // 16384 steps per block
        const int    k0    = q * STEPS;
        const size_t sbase = (size_t)b * NP + k0;
        const int4*  p4    = (const int4*)pw;

        if (!is64) {
            // int32 layout: one int4 = 2 pairs; lane-consecutive -> coalesced.
            constexpr int NIT = STEPS / (THREADS * 2);   // 16
            constexpr int NCH = NIT / 8;                 // 2
            const size_t pb = sbase >> 1;
            int bval = -1;
            if (lane < NIT) {
                const int kf = k0 + (lane * THREADS + wbase) * 2;
                if (kf != 0) bval = pw[2 * ((size_t)b * NP + kf) - 1];
            }
            #pragma unroll
            for (int ch = 0; ch < NCH; ++ch) {
                int4 a[8];
                #pragma unroll
                for (int j = 0; j < 8; ++j) a[j] = p4[pb + (ch * 8 + j) * THREADS + tid];
                #pragma unroll
                for (int j = 0; j < 8; ++j) {
                    const int it = ch * 8 + j;
                    const int pi0 = a[j].x, pj0 = a[j].y, pi1 = a[j].z, pj1 = a[j].w;
                    const int pl = __shfl_up(pj1, 1);
                    const int bv = __shfl(bval, it);
                    const int prev = (lane == 0) ? bv : pl;
                    const bool f0 = (pj0 != prev);
                    const bool f1 = (pj1 != pj0);
                    if (f0 && ((tbits[pj0 >> 5] >> (pj0 & 31)) & 1u))
                        atomicOr(&gbits[pi0 >> 5], 1u << (pi0 & 31));
                    if (f1 && ((tbits[pj1 >> 5] >> (pj1 & 31)) & 1u))
                        atomicOr(&gbits[pi1 >> 5], 1u << (pi1 & 31));
                }
            }
        } else {
            // int64 layout: one int4 = 1 pair (pi=x, pj=z).
            constexpr int NIT = STEPS / THREADS;         // 32
            constexpr int NCH = NIT / 8;                 // 4
            int bval = -1;
            if (lane < NIT) {
                const int kf = k0 + lane * THREADS + wbase;
                if (kf != 0) bval = pw[4 * ((size_t)b * NP + kf) - 2];
            }
            #pragma unroll
            for (int ch = 0; ch < NCH; ++ch) {
                int4 a[8];
                #pragma unroll
                for (int j = 0; j < 8; ++j) a[j] = p4[sbase + (ch * 8 + j) * THREADS + tid];
                #pragma unroll
                for (int j = 0; j < 8; ++j) {
                    const int it = ch * 8 + j;
                    const int pi = a[j].x, pj = a[j].z;
                    const int pl = __shfl_up(pj, 1);
                    const int bv = __shfl(bval, it);
                    const int prev = (lane == 0) ? bv : pl;
                    if ((pj != prev) && ((tbits[pj >> 5] >> (pj & 31)) & 1u))
                        atomicOr(&gbits[pi >> 5], 1u << (pi & 31));
                }
            }
        }
        __syncthreads();

        unsigned int* dst = pmask + (size_t)q * MASK_WORDS + (size_t)b * WPB;
        dst[tid]       = gbits[tid];
        dst[tid + 512] = gbits[tid + 512];
    }
    grid.sync();

    // ---- Phase 3: streaming loss partials (float4, OR of QPB planes) ----
    {
        constexpr int N4 = (NB * NS) / 4;   // 1,048,576 float4s
        float acc = 0.f;
        for (int idx = bid * THREADS + tid; idx < N4; idx += BLOCKS * THREADS) {
            const float4 x = reinterpret_cast<const float4*>(preds)[idx];
            unsigned int mw = 0u;
            #pragma unroll
            for (int q = 0; q < QPB; ++q)
                mw |= pmask[(size_t)q * MASK_WORDS + (idx >> 3)];
            const unsigned int m = mw >> ((idx & 7) * 4);
            const float xs[4] = {x.x, x.y, x.z, x.w};
            #pragma unroll
            for (int j = 0; j < 4; ++j) {
                const float v = xs[j];
                // stable softplus: sp(v)=log(1+exp(-|v|))+max(v,0); sp(-v)=sp(v)-v
                const float t = __logf(1.f + __expf(-fabsf(v)));
                const float sp_pos = t + fmaxf(v, 0.f);
                const float sp_neg = sp_pos - v;
                acc += ((m >> j) & 1u) ? POS_W * sp_neg : sp_pos;
            }
        }
        for (int off = 32; off; off >>= 1) acc += __shfl_down(acc, off);
        if (lane == 0) sacc[tid >> 6] = acc;
        __syncthreads();
        if (tid == 0) {
            float s = 0.f;
            #pragma unroll
            for (int w = 0; w < 8; ++w) s += sacc[w];
            partials[bid] = s;
        }
    }
    grid.sync();

    // ---- Phase 4: block 0 final reduce ----
    if (bid == 0) {
        float acc = partials[tid];                 // BLOCKS == THREADS == 512
        for (int off = 32; off; off >>= 1) acc += __shfl_down(acc, off);
        if (lane == 0) sacc[tid >> 6] = acc;
        __syncthreads();
        if (tid == 0) {
            float s = 0.f;
            #pragma unroll
            for (int w = 0; w < 8; ++w) s += sacc[w];
            out[0] = s * (1.0f / ((float)NB * (float)NS));
        }
    }
}

// ---------------------------------------------------------------------------
extern "C" void kernel_launch(void* const* d_in, const int* in_sizes, int n_in,
                              void* d_out, int out_size, void* d_ws, size_t ws_size,
                              hipStream_t stream) {
    const float* preds   = (const float*)d_in[0];
    const int*   targets = (const int*)d_in[1];
    const int*   paths_w = (const int*)d_in[2];   // int32 words; layout auto-detected
    float*       out     = (float*)d_out;

    unsigned int* tbits_g  = (unsigned int*)d_ws;
    unsigned int* pmask    = tbits_g + MASK_WORDS;
    float*        partials = (float*)((char*)d_ws +
                              (size_t)(1 + QPB) * MASK_WORDS * 4);

    void* args[] = {(void*)&preds, (void*)&targets, (void*)&paths_w,
                    (void*)&tbits_g, (void*)&pmask, (void*)&partials, (void*)&out};
    hipLaunchCooperativeKernel((const void*)fused_kernel,
                               dim3(BLOCKS), dim3(THREADS), args, 0, stream);
}

// Round 11
// 33.425 us; speedup vs baseline: 5.6031x; 5.6031x over previous
//
#include <hip/hip_runtime.h>

// Problem constants (fixed by the reference's setup_inputs):
//   B=128 batches, S=32768 sequence, P=65536 path steps.
#define NB 128
#define NS 32768
#define NP 65536
#define POS_W 5.0f

constexpr int MASK_WORDS = (NB * NS) / 32;   // 131072 words = 512 KB per mask plane
constexpr int WPB        = NS / 32;          // 1024 mask words per batch (4 KB)
constexpr int LOSS_BLOCKS = 512;             // chunked loss: 2048 float4s per block
constexpr int CHUNK4      = (NB * NS / 4) / LOSS_BLOCKS;  // 2048
constexpr int MWPC        = CHUNK4 / 8;      // 256 mask words per chunk

// ws layout:
//   [0, MASK_WORDS*4)                     : global targets bitmap (tbits)
//   [MASK_WORDS*4, +QPB*MASK_WORDS*4)     : QPB partial gt-mask planes
//   [after planes]                        : per-block loss partials (2 KB)
//
// Journal: no hipMemsetAsync for small regions (R7); no mid-stream
// device-scope __threadfence fan-in (R8: -25us); NO grid.sync cooperative
// fusion (R10: 187us -- grid barriers across 8 non-coherent XCDs are ~50us
// each). Serial dispatches + fence-free partials is the proven-fast shape.

// ---------------------------------------------------------------------------
// One-shot: targets (16 MB int32) -> 512 KB bitmap, via per-wave ballot.
__global__ __launch_bounds__(256)
void tbit_kernel(const int* __restrict__ targets, unsigned int* __restrict__ tb) {
    constexpr int NSEG = NB * NS / 64;
    const int lane = threadIdx.x & 63;
    const int wid  = (blockIdx.x * blockDim.x + threadIdx.x) >> 6;
    const int nw   = (gridDim.x * blockDim.x) >> 6;
    for (int s = wid; s < NSEG; s += nw) {
        const unsigned long long m = __ballot(targets[(size_t)s * 64 + lane] != 0);
        if (lane == 0)       tb[s * 2]     = (unsigned int)m;
        else if (lane == 32) tb[s * 2 + 1] = (unsigned int)(m >> 32);
    }
}

// ---------------------------------------------------------------------------
// One block = (batch b, plane q), 512 threads. Lane-consecutive (coalesced)
// int4 loads, iterations hoisted into registers (deep MLP). prev-pj via shfl;
// per-wave boundary values prefetched by lanes 0..NIT-1 before the loop.
// Random accesses stay in LDS (ds_or atomics).
template <int QPB>
__global__ __launch_bounds__(512)
void gt_kernel(const int* __restrict__ pw, const unsigned int* __restrict__ tbits_g,
               unsigned int* __restrict__ pmask) {
    __shared__ unsigned int tbits[WPB];   // 4 KB: targets[b] as bits
    __shared__ unsigned int gbits[WPB];   // 4 KB: this block's gt-bit plane

    // Layout detect (uniform scalar): int64 -> hi word of last elem == 0.
    const int is64 = (pw[2 * (size_t)NP - 1] == 0);

    const int q    = blockIdx.x;
    const int b    = blockIdx.y;
    const int tid  = threadIdx.x;         // 0..511
    const int lane = tid & 63;
    const int wbase = tid & ~63;          // wave's base tid

    tbits[tid]       = tbits_g[(size_t)b * WPB + tid];
    tbits[tid + 512] = tbits_g[(size_t)b * WPB + tid + 512];
    gbits[tid]       = 0u;
    gbits[tid + 512] = 0u;
    __syncthreads();

    constexpr int STEPS = NP / QPB;              // steps per block (8192 @ QPB=8)
    const int    k0    = q * STEPS;              // batch-local base step
    const size_t sbase = (size_t)b * NP + k0;    // global base step
    const int4*  p4    = (const int4*)pw;

    if (!is64) {
        // int32 layout: one int4 = 2 pairs; lane-consecutive -> coalesced.
        constexpr int NIT = STEPS / 1024;        // 8 @ QPB=8
        constexpr int NCH = (NIT + 7) / 8;
        const size_t pb = sbase >> 1;
        int bval = -1;
        if (lane < NIT) {
            const int kf = k0 + (lane * 512 + wbase) * 2;
            if (kf != 0) bval = pw[2 * ((size_t)b * NP + kf) - 1];
        }
        #pragma unroll
        for (int ch = 0; ch < NCH; ++ch) {
            int4 a[8];
            #pragma unroll
            for (int j = 0; j < 8; ++j) a[j] = p4[pb + (ch * 8 + j) * 512 + tid];
            #pragma unroll
            for (int j = 0; j < 8; ++j) {
                const int it = ch * 8 + j;
                const int pi0 = a[j].x, pj0 = a[j].y, pi1 = a[j].z, pj1 = a[j].w;
                const int pl = __shfl_up(pj1, 1);
                const int bv = __shfl(bval, it);
                const int prev = (lane == 0) ? bv : pl;
                const bool f0 = (pj0 != prev);
                const bool f1 = (pj1 != pj0);
                if (f0 && ((tbits[pj0 >> 5] >> (pj0 & 31)) & 1u))
                    atomicOr(&gbits[pi0 >> 5], 1u << (pi0 & 31));
                if (f1 && ((tbits[pj1 >> 5] >> (pj1 & 31)) & 1u))
                    atomicOr(&gbits[pi1 >> 5], 1u << (pi1 & 31));
            }
        }
    } else {
        // int64 layout: one int4 = 1 pair (pi=x, pj=z); lane-consecutive.
        constexpr int NIT = STEPS / 512;         // 16 @ QPB=8
        constexpr int NCH = (NIT + 7) / 8;
        int bval = -1;
        if (lane < NIT) {
            const int kf = k0 + lane * 512 + wbase;
            if (kf != 0) bval = pw[4 * ((size_t)b * NP + kf) - 2];
        }
        #pragma unroll
        for (int ch = 0; ch < NCH; ++ch) {
            int4 a[8];
            #pragma unroll
            for (int j = 0; j < 8; ++j) a[j] = p4[sbase + (ch * 8 + j) * 512 + tid];
            #pragma unroll
            for (int j = 0; j < 8; ++j) {
                const int it = ch * 8 + j;
                const int pi = a[j].x, pj = a[j].z;
                const int pl = __shfl_up(pj, 1);
                const int bv = __shfl(bval, it);
                const int prev = (lane == 0) ? bv : pl;
                if ((pj != prev) && ((tbits[pj >> 5] >> (pj & 31)) & 1u))
                    atomicOr(&gbits[pi >> 5], 1u << (pi & 31));
            }
        }
    }
    __syncthreads();

    unsigned int* dst = pmask + (size_t)q * MASK_WORDS + (size_t)b * WPB;
    dst[tid]       = gbits[tid];
    dst[tid + 512] = gbits[tid + 512];
}

// ---------------------------------------------------------------------------
// Chunked streaming loss: each block owns a contiguous 2048-float4 chunk.
// The QPB planes' 256 mask words are OR-merged into LDS ONCE (coalesced),
// then preds stream with LDS-broadcast mask reads (1 global load per float4
// instead of 1+QPB). Fence-free deterministic partials.
template <int QPB>
__global__ __launch_bounds__(256)
void loss_kernel(const float* __restrict__ preds, const unsigned int* __restrict__ pmask,
                 float* __restrict__ partials) {
    __shared__ unsigned int mmask[MWPC];  // 1 KB merged mask for this chunk
    const int tid = threadIdx.x;
    const int cb4 = blockIdx.x * CHUNK4;  // chunk base (float4 units)
    const int mb  = blockIdx.x * MWPC;    // chunk base (mask words)

    unsigned int mw = 0u;
    #pragma unroll
    for (int q = 0; q < QPB; ++q)
        mw |= pmask[(size_t)q * MASK_WORDS + mb + tid];
    mmask[tid] = mw;
    __syncthreads();

    float acc = 0.f;
    #pragma unroll
    for (int it = 0; it < CHUNK4 / 256; ++it) {
        const int li = it * 256 + tid;    // local float4 index
        const float4 x = reinterpret_cast<const float4*>(preds)[cb4 + li];
        const unsigned int m = mmask[li >> 3] >> ((li & 7) * 4);
        const float xs[4] = {x.x, x.y, x.z, x.w};
        #pragma unroll
        for (int j = 0; j < 4; ++j) {
            const float v = xs[j];
            // stable softplus: sp(v)=log(1+exp(-|v|))+max(v,0); sp(-v)=sp(v)-v
            const float t = __logf(1.f + __expf(-fabsf(v)));
            const float sp_pos = t + fmaxf(v, 0.f);
            const float sp_neg = sp_pos - v;
            acc += ((m >> j) & 1u) ? POS_W * sp_neg : sp_pos;
        }
    }
    for (int off = 32; off; off >>= 1) acc += __shfl_down(acc, off);
    __shared__ float sacc[4];
    const int wave = tid >> 6, lane = tid & 63;
    if (lane == 0) sacc[wave] = acc;
    __syncthreads();
    if (tid == 0) {
        float s = 0.f;
        #pragma unroll
        for (int w = 0; w < 4; ++w) s += sacc[w];
        partials[blockIdx.x] = s;
    }
}

// ---------------------------------------------------------------------------
__global__ __launch_bounds__(256)
void final_kernel(const float* __restrict__ partials, float* __restrict__ out) {
    float acc = 0.f;
    for (int i = threadIdx.x; i < LOSS_BLOCKS; i += 256) acc += partials[i];
    for (int off = 32; off; off >>= 1) acc += __shfl_down(acc, off);
    __shared__ float sacc[4];
    const int wave = threadIdx.x >> 6, lane = threadIdx.x & 63;
    if (lane == 0) sacc[wave] = acc;
    __syncthreads();
    if (threadIdx.x == 0) {
        float s = 0.f;
        #pragma unroll
        for (int w = 0; w < 4; ++w) s += sacc[w];
        out[0] = s * (1.0f / ((float)NB * (float)NS));
    }
}

// ---------------------------------------------------------------------------
extern "C" void kernel_launch(void* const* d_in, const int* in_sizes, int n_in,
                              void* d_out, int out_size, void* d_ws, size_t ws_size,
                              hipStream_t stream) {
    const float* preds   = (const float*)d_in[0];
    const int*   targets = (const int*)d_in[1];
    const int*   paths_w = (const int*)d_in[2];   // int32 words; layout auto-detected
    float*       out     = (float*)d_out;

    // Pick planes-per-batch by available workspace (deterministic for fixed ws).
    int qpb = 8;
    while (qpb > 2 &&
           ws_size < (size_t)(1 + qpb) * MASK_WORDS * 4 + (size_t)LOSS_BLOCKS * 4)
        qpb >>= 1;

    unsigned int* tbits_g  = (unsigned int*)d_ws;
    unsigned int* pmask    = tbits_g + MASK_WORDS;
    float*        partials = (float*)((char*)d_ws +
                              (size_t)(1 + qpb) * MASK_WORDS * 4);

    tbit_kernel<<<1024, 256, 0, stream>>>(targets, tbits_g);

    dim3 g1(qpb, NB);
    switch (qpb) {
        case 8:
            gt_kernel<8><<<g1, 512, 0, stream>>>(paths_w, tbits_g, pmask);
            loss_kernel<8><<<LOSS_BLOCKS, 256, 0, stream>>>(preds, pmask, partials);
            break;
        case 4:
            gt_kernel<4><<<g1, 512, 0, stream>>>(paths_w, tbits_g, pmask);
            loss_kernel<4><<<LOSS_BLOCKS, 256, 0, stream>>>(preds, pmask, partials);
            break;
        default:
            gt_kernel<2><<<g1, 512, 0, stream>>>(paths_w, tbits_g, pmask);
            loss_kernel<2><<<LOSS_BLOCKS, 256, 0, stream>>>(preds, pmask, partials);
            break;
    }

    final_kernel<<<1, 256, 0, stream>>>(partials, out);
}